// Round 1
// baseline (694.980 us; speedup 1.0000x reference)
//
#include <hip/hip_runtime.h>
#include <hip/hip_bf16.h>

namespace {

constexpr int T_LEN = 336;
constexpr int D_IN  = 8;
constexpr int NH1   = 96;   // layer1 hidden
constexpr int NH2   = 64;   // layer2 hidden
constexpr int HOR   = 24;   // output horizon
constexpr int BM    = 16;   // batch rows per workgroup
constexpr int KPAD  = 200;  // LDS row stride in bf16 elems: 400 B, 16B-aligned, bank step 4

// Hc slot layout (per batch row): [0,64)=h2, [64,160)=h1, [160,168)=x_t, [168,192)=zero pad

typedef __attribute__((ext_vector_type(8))) short short8;
typedef __attribute__((ext_vector_type(4))) float f32x4;

__device__ inline unsigned short f2b(float f) {
  union { float f; unsigned u; } v; v.f = f;
  unsigned r = v.u + 0x7fffu + ((v.u >> 16) & 1u);   // RNE to bf16
  return (unsigned short)(r >> 16);
}

__device__ inline short8 pack8(float4 p0, float4 p1) {
  short8 f;
  f[0]=(short)f2b(p0.x); f[1]=(short)f2b(p0.y); f[2]=(short)f2b(p0.z); f[3]=(short)f2b(p0.w);
  f[4]=(short)f2b(p1.x); f[5]=(short)f2b(p1.y); f[6]=(short)f2b(p1.z); f[7]=(short)f2b(p1.w);
  return f;
}

__device__ inline float sigf(float x)   { return 1.0f / (1.0f + __expf(-x)); }
__device__ inline float tanhf_(float x) { return 1.0f - 2.0f / (1.0f + __expf(2.0f * x)); }

__global__ __launch_bounds__(512, 2) void lstm_forecaster(
    const float* __restrict__ x,
    const float* __restrict__ Wih1, const float* __restrict__ Whh1,
    const float* __restrict__ bih1, const float* __restrict__ bhh1,
    const float* __restrict__ Wih2, const float* __restrict__ Whh2,
    const float* __restrict__ bih2, const float* __restrict__ bhh2,
    const float* __restrict__ fc1w, const float* __restrict__ fc1b,
    const float* __restrict__ fcow, const float* __restrict__ fcob,
    float* __restrict__ out)
{
  __shared__ unsigned short Hc[BM * KPAD];
  __shared__ float h2f[BM][NH2];
  __shared__ float fcb[BM][NH2 + 4];

  const int tid  = threadIdx.x;
  const int w    = tid >> 6;   // wave id 0..7
  const int l    = tid & 63;   // lane
  const int lrow = l & 15;     // MFMA A-row / B-col / D-col
  const int lgrp = l >> 4;     // 0..3
  const int b0   = blockIdx.x * BM;

  // zero LDS state (h1=h2=0, pad region stays 0 forever)
  for (int i = tid; i < BM * KPAD; i += 512) Hc[i] = 0;

  // ---------- weight A-fragments, row-permuted so lane's 4 acc regs = i,f,g,o of one cell ----------
  // layer1: wave w owns cells [12w,12w+12); within tile mt, A-row (4h+g) <-> cell 12w+4mt+h, gate g
  short8 a1[3][4];
  #pragma unroll
  for (int mt = 0; mt < 3; ++mt) {
    const int gate = lrow & 3;
    const int cell = w * 12 + mt * 4 + (lrow >> 2);
    const int wrow = NH1 * gate + cell;            // row in [0,384)
    #pragma unroll
    for (int kt = 0; kt < 4; ++kt) {
      const int kb = kt * 32 + lgrp * 8;           // k base for this lane's 8 elems
      if (kb < NH1) {
        a1[mt][kt] = pack8(*(const float4*)(Whh1 + wrow * NH1 + kb),
                           *(const float4*)(Whh1 + wrow * NH1 + kb + 4));
      } else if (kb == NH1) {
        a1[mt][kt] = pack8(*(const float4*)(Wih1 + wrow * D_IN),
                           *(const float4*)(Wih1 + wrow * D_IN + 4));
      } else {
        short8 z; 
        #pragma unroll
        for (int e = 0; e < 8; ++e) z[e] = 0;
        a1[mt][kt] = z;
      }
    }
  }
  // layer2: wave w owns cells [8w,8w+8); A2 = [Whh2 | Wih2], K = 64 + 96 = 160
  short8 a2[2][5];
  #pragma unroll
  for (int mt = 0; mt < 2; ++mt) {
    const int gate = lrow & 3;
    const int cell = w * 8 + mt * 4 + (lrow >> 2);
    const int wrow = NH2 * gate + cell;            // row in [0,256)
    #pragma unroll
    for (int kt = 0; kt < 5; ++kt) {
      const int kb = kt * 32 + lgrp * 8;
      if (kb < NH2) {
        a2[mt][kt] = pack8(*(const float4*)(Whh2 + wrow * NH2 + kb),
                           *(const float4*)(Whh2 + wrow * NH2 + kb + 4));
      } else {
        a2[mt][kt] = pack8(*(const float4*)(Wih2 + wrow * NH1 + (kb - NH2)),
                           *(const float4*)(Wih2 + wrow * NH1 + (kb - NH2) + 4));
      }
    }
  }

  // biases: acc reg r of lane <-> gate r of cell (uses lgrp, per C/D layout row=4*lgrp+r)
  float bias1[3][4], bias2[2][4];
  #pragma unroll
  for (int mt = 0; mt < 3; ++mt) {
    const int cell = w * 12 + mt * 4 + lgrp;
    #pragma unroll
    for (int r = 0; r < 4; ++r)
      bias1[mt][r] = bih1[NH1 * r + cell] + bhh1[NH1 * r + cell];
  }
  #pragma unroll
  for (int mt = 0; mt < 2; ++mt) {
    const int cell = w * 8 + mt * 4 + lgrp;
    #pragma unroll
    for (int r = 0; r < 4; ++r)
      bias2[mt][r] = bih2[NH2 * r + cell] + bhh2[NH2 * r + cell];
  }

  // x streaming: wave0 lane covers (col=lrow, float-pair j=lgrp)
  const float* xrow = x + (size_t)(b0 + lrow) * (T_LEN * D_IN) + lgrp * 2;
  float2 xv = make_float2(0.0f, 0.0f);
  if (w == 0) xv = *(const float2*)(xrow);         // x(t=0)
  __syncthreads();                                  // Hc zero visible
  if (w == 0) {
    unsigned p = (unsigned)f2b(xv.x) | ((unsigned)f2b(xv.y) << 16);
    *(unsigned*)&Hc[lrow * KPAD + 160 + lgrp * 2] = p;
  }
  __syncthreads();                                  // x(0) visible

  float c1[3] = {0.0f, 0.0f, 0.0f};
  float c2[2] = {0.0f, 0.0f};
  const unsigned short* bp1 = &Hc[lrow * KPAD + 64 + lgrp * 8];  // B1: [h1|x|pad]
  const unsigned short* bp2 = &Hc[lrow * KPAD + lgrp * 8];       // B2: [h2|h1]
  unsigned short* hw1 = &Hc[lrow * KPAD + 64 + w * 12 + lgrp];
  unsigned short* hw2 = &Hc[lrow * KPAD + w * 8 + lgrp];

  for (int t = 0; t < T_LEN; ++t) {
    // ---- layer 1: gates^T = [Whh1|Wih1] * [h1|x]^T + b ----
    short8 b1[4];
    #pragma unroll
    for (int kt = 0; kt < 4; ++kt)
      b1[kt] = *(const short8*)(bp1 + kt * 32);

    if (w == 0 && t + 1 < T_LEN)                    // prefetch x(t+1), hidden under MFMA
      xv = *(const float2*)(xrow + (t + 1) * D_IN);

    float h1v[3];
    #pragma unroll
    for (int mt = 0; mt < 3; ++mt) {
      f32x4 acc = { bias1[mt][0], bias1[mt][1], bias1[mt][2], bias1[mt][3] };
      #pragma unroll
      for (int kt = 0; kt < 4; ++kt)
        acc = __builtin_amdgcn_mfma_f32_16x16x32_bf16(a1[mt][kt], b1[kt], acc, 0, 0, 0);
      const float ig = sigf(acc[0]);
      const float fg = sigf(acc[1]);
      const float gg = tanhf_(acc[2]);
      const float og = sigf(acc[3]);
      c1[mt] = fg * c1[mt] + ig * gg;
      h1v[mt] = og * tanhf_(c1[mt]);
    }

    __syncthreads();                                // all B1 reads consumed
    #pragma unroll
    for (int mt = 0; mt < 3; ++mt)
      hw1[mt * 4] = f2b(h1v[mt]);
    if (w == 0 && t + 1 < T_LEN) {
      unsigned p = (unsigned)f2b(xv.x) | ((unsigned)f2b(xv.y) << 16);
      *(unsigned*)&Hc[lrow * KPAD + 160 + lgrp * 2] = p;
    }
    __syncthreads();                                // h1(t), x(t+1) visible

    // ---- layer 2: gates^T = [Whh2|Wih2] * [h2|h1_new]^T + b ----
    short8 b2[5];
    #pragma unroll
    for (int kt = 0; kt < 5; ++kt)
      b2[kt] = *(const short8*)(bp2 + kt * 32);

    float h2v[2];
    #pragma unroll
    for (int mt = 0; mt < 2; ++mt) {
      f32x4 acc = { bias2[mt][0], bias2[mt][1], bias2[mt][2], bias2[mt][3] };
      #pragma unroll
      for (int kt = 0; kt < 5; ++kt)
        acc = __builtin_amdgcn_mfma_f32_16x16x32_bf16(a2[mt][kt], b2[kt], acc, 0, 0, 0);
      const float ig = sigf(acc[0]);
      const float fg = sigf(acc[1]);
      const float gg = tanhf_(acc[2]);
      const float og = sigf(acc[3]);
      c2[mt] = fg * c2[mt] + ig * gg;
      h2v[mt] = og * tanhf_(c2[mt]);
    }

    __syncthreads();                                // all B2 reads consumed
    #pragma unroll
    for (int mt = 0; mt < 2; ++mt)
      hw2[mt * 4] = f2b(h2v[mt]);
    if (t == T_LEN - 1) {                           // keep final h2 in fp32 for the FC head
      #pragma unroll
      for (int mt = 0; mt < 2; ++mt)
        h2f[lrow][w * 8 + mt * 4 + lgrp] = h2v[mt];
    }
  }

  __syncthreads();

  // ---- FC head: out = relu(h2 @ fc1w^T + fc1b) @ fcow^T + fcob ----
  for (int p = tid; p < BM * NH2; p += 512) {
    const int col = p >> 6;
    const int j   = p & 63;
    float s = fc1b[j];
    const float* wr = fc1w + j * NH2;
    #pragma unroll 8
    for (int k = 0; k < NH2; ++k) s += h2f[col][k] * wr[k];
    fcb[col][j] = fmaxf(s, 0.0f);
  }
  __syncthreads();
  if (tid < BM * HOR) {
    const int col = tid / HOR;
    const int oc  = tid - col * HOR;
    float s = fcob[oc];
    const float* wr = fcow + oc * NH2;
    #pragma unroll 8
    for (int k = 0; k < NH2; ++k) s += fcb[col][k] * wr[k];
    out[(size_t)(b0 + col) * HOR + oc] = s;
  }
}

} // namespace

extern "C" void kernel_launch(void* const* d_in, const int* in_sizes, int n_in,
                              void* d_out, int out_size, void* d_ws, size_t ws_size,
                              hipStream_t stream) {
  const float* x    = (const float*)d_in[0];
  const float* Wih1 = (const float*)d_in[1];
  const float* Whh1 = (const float*)d_in[2];
  const float* bih1 = (const float*)d_in[3];
  const float* bhh1 = (const float*)d_in[4];
  const float* Wih2 = (const float*)d_in[5];
  const float* Whh2 = (const float*)d_in[6];
  const float* bih2 = (const float*)d_in[7];
  const float* bhh2 = (const float*)d_in[8];
  const float* fc1w = (const float*)d_in[9];
  const float* fc1b = (const float*)d_in[10];
  const float* fcow = (const float*)d_in[11];
  const float* fcob = (const float*)d_in[12];
  float* out = (float*)d_out;

  const int Btot = in_sizes[0] / (T_LEN * D_IN);   // 4096
  const int nblk = Btot / BM;                       // 256 workgroups

  lstm_forecaster<<<dim3(nblk), dim3(512), 0, stream>>>(
      x, Wih1, Whh1, bih1, bhh1, Wih2, Whh2, bih2, bhh2,
      fc1w, fc1b, fcow, fcob, out);
}

// Round 2
// 361.644 us; speedup vs baseline: 1.9217x; 1.9217x over previous
//
#include <hip/hip_runtime.h>
#include <hip/hip_bf16.h>

namespace {

constexpr int T_LEN = 336;
constexpr int D_IN  = 8;
constexpr int NH1   = 96;   // layer1 hidden
constexpr int NH2   = 64;   // layer2 hidden
constexpr int HOR   = 24;   // output horizon
constexpr int BM    = 16;   // batch rows per workgroup
constexpr int KPAD  = 200;  // LDS row stride (bf16 elems): 400 B, 16B-aligned

// Per-row slot layout in each state buffer:
//   [0,64)=h2, [64,160)=h1, [160,168)=x_t, [168,192)=zero pad (never written)

typedef __attribute__((ext_vector_type(8))) short short8;
typedef __attribute__((ext_vector_type(4))) float f32x4;

__device__ inline unsigned short f2b(float f) {
  union { float f; unsigned u; } v; v.f = f;
  unsigned r = v.u + 0x7fffu + ((v.u >> 16) & 1u);   // RNE to bf16
  return (unsigned short)(r >> 16);
}

__device__ inline short8 pack8(float4 p0, float4 p1) {
  short8 f;
  f[0]=(short)f2b(p0.x); f[1]=(short)f2b(p0.y); f[2]=(short)f2b(p0.z); f[3]=(short)f2b(p0.w);
  f[4]=(short)f2b(p1.x); f[5]=(short)f2b(p1.y); f[6]=(short)f2b(p1.z); f[7]=(short)f2b(p1.w);
  return f;
}

// fast activations: v_rcp_f32 instead of the precise-divide sequence.
// rcp is ~1 ulp; bf16 state rounding (4e-3 rel) dominates by 4 orders.
__device__ inline float sigf(float x)   { return __builtin_amdgcn_rcpf(1.0f + __expf(-x)); }
__device__ inline float tanhf_(float x) { return 1.0f - 2.0f * __builtin_amdgcn_rcpf(1.0f + __expf(2.0f * x)); }

__global__ __launch_bounds__(512, 2) void lstm_forecaster(
    const float* __restrict__ x,
    const float* __restrict__ Wih1, const float* __restrict__ Whh1,
    const float* __restrict__ bih1, const float* __restrict__ bhh1,
    const float* __restrict__ Wih2, const float* __restrict__ Whh2,
    const float* __restrict__ bih2, const float* __restrict__ bhh2,
    const float* __restrict__ fc1w, const float* __restrict__ fc1b,
    const float* __restrict__ fcow, const float* __restrict__ fcob,
    float* __restrict__ out)
{
  __shared__ unsigned short Hc[2][BM * KPAD];   // double-buffered state
  __shared__ float h2f[BM][NH2];
  __shared__ float fcb[BM][NH2 + 4];

  const int tid  = threadIdx.x;
  const int w    = tid >> 6;   // wave id 0..7
  const int l    = tid & 63;   // lane
  const int lrow = l & 15;     // MFMA A-row / B-col / D-col (batch row)
  const int lgrp = l >> 4;     // 0..3
  const int b0   = blockIdx.x * BM;

  // x streaming: wave0 lane covers (row=lrow, float-pair j=lgrp)
  const float* xrow = x + (size_t)(b0 + lrow) * (T_LEN * D_IN) + lgrp * 2;
  float2 xv = make_float2(0.0f, 0.0f);
  if (w == 0) xv = *(const float2*)(xrow);          // x(0), issued early

  // zero both state buffers (h=0, pad stays 0 forever)
  for (int i = tid; i < 2 * BM * KPAD; i += 512) ((unsigned short*)Hc)[i] = 0;

  // ---------- weight A-fragments, row-permuted so lane's 4 acc regs = i,f,g,o of one cell ----------
  // layer1: wave w owns cells [12w,12w+12); K = [h1(96) | x(8) | pad(24)] = 128
  short8 a1[3][4];
  #pragma unroll
  for (int mt = 0; mt < 3; ++mt) {
    const int gate = lrow & 3;
    const int cell = w * 12 + mt * 4 + (lrow >> 2);
    const int wrow = NH1 * gate + cell;             // row in [0,384)
    #pragma unroll
    for (int kt = 0; kt < 4; ++kt) {
      const int kb = kt * 32 + lgrp * 8;
      if (kb < NH1) {
        a1[mt][kt] = pack8(*(const float4*)(Whh1 + wrow * NH1 + kb),
                           *(const float4*)(Whh1 + wrow * NH1 + kb + 4));
      } else if (kb == NH1) {
        a1[mt][kt] = pack8(*(const float4*)(Wih1 + wrow * D_IN),
                           *(const float4*)(Wih1 + wrow * D_IN + 4));
      } else {
        short8 z;
        #pragma unroll
        for (int e = 0; e < 8; ++e) z[e] = 0;
        a1[mt][kt] = z;
      }
    }
  }
  // layer2: wave w owns cells [8w,8w+8); K = [h2(64) | h1(96)] = 160
  short8 a2[2][5];
  #pragma unroll
  for (int mt = 0; mt < 2; ++mt) {
    const int gate = lrow & 3;
    const int cell = w * 8 + mt * 4 + (lrow >> 2);
    const int wrow = NH2 * gate + cell;             // row in [0,256)
    #pragma unroll
    for (int kt = 0; kt < 5; ++kt) {
      const int kb = kt * 32 + lgrp * 8;
      if (kb < NH2) {
        a2[mt][kt] = pack8(*(const float4*)(Whh2 + wrow * NH2 + kb),
                           *(const float4*)(Whh2 + wrow * NH2 + kb + 4));
      } else {
        a2[mt][kt] = pack8(*(const float4*)(Wih2 + wrow * NH1 + (kb - NH2)),
                           *(const float4*)(Wih2 + wrow * NH1 + (kb - NH2) + 4));
      }
    }
  }

  // biases: acc reg r of lane <-> gate r of cell (C/D layout row = 4*lgrp + r)
  float bias1[3][4], bias2[2][4];
  #pragma unroll
  for (int mt = 0; mt < 3; ++mt) {
    const int cell = w * 12 + mt * 4 + lgrp;
    #pragma unroll
    for (int r = 0; r < 4; ++r)
      bias1[mt][r] = bih1[NH1 * r + cell] + bhh1[NH1 * r + cell];
  }
  #pragma unroll
  for (int mt = 0; mt < 2; ++mt) {
    const int cell = w * 8 + mt * 4 + lgrp;
    #pragma unroll
    for (int r = 0; r < 4; ++r)
      bias2[mt][r] = bih2[NH2 * r + cell] + bhh2[NH2 * r + cell];
  }

  __syncthreads();                                  // zeros visible
  if (w == 0) {                                     // stage x(0) into buf1 (read buf of phase -1)
    unsigned p = (unsigned)f2b(xv.x) | ((unsigned)f2b(xv.y) << 16);
    *(unsigned*)&Hc[1][lrow * KPAD + 160 + lgrp * 2] = p;
  }
  __syncthreads();                                  // x(0) visible

  float c1[3] = {0.0f, 0.0f, 0.0f};
  float c2[2] = {0.0f, 0.0f};
  const int rbo = lrow * KPAD;                      // per-row base offset

  // ---------- phase -1 (peeled): L1(0) only; reads buf1, writes buf0 ----------
  {
    if (w == 0) xv = *(const float2*)(xrow + D_IN); // prefetch x(1)
    short8 b1[4];
    #pragma unroll
    for (int kt = 0; kt < 4; ++kt)
      b1[kt] = *(const short8*)(&Hc[1][rbo + 64 + lgrp * 8 + kt * 32]);
    #pragma unroll
    for (int mt = 0; mt < 3; ++mt) {
      f32x4 acc = { bias1[mt][0], bias1[mt][1], bias1[mt][2], bias1[mt][3] };
      #pragma unroll
      for (int kt = 0; kt < 4; ++kt)
        acc = __builtin_amdgcn_mfma_f32_16x16x32_bf16(a1[mt][kt], b1[kt], acc, 0, 0, 0);
      const float ig = sigf(acc[0]), fg = sigf(acc[1]);
      const float gg = tanhf_(acc[2]), og = sigf(acc[3]);
      c1[mt] = fg * c1[mt] + ig * gg;
      Hc[0][rbo + 64 + w * 12 + mt * 4 + lgrp] = f2b(og * tanhf_(c1[mt]));
    }
    if (w == 0) {
      unsigned p = (unsigned)f2b(xv.x) | ((unsigned)f2b(xv.y) << 16);
      *(unsigned*)&Hc[0][lrow * KPAD + 160 + lgrp * 2] = p;
    }
    __syncthreads();
  }

  // ---------- main loop: phase p does L2(p) + L1(p+1); ONE barrier per step ----------
  for (int p = 0; p < T_LEN - 1; ++p) {
    const unsigned short* RB = &Hc[p & 1][0];
    unsigned short*       WB = &Hc[(p & 1) ^ 1][0];

    if (w == 0 && p + 2 < T_LEN)                    // x(p+2), hidden under the whole phase
      xv = *(const float2*)(xrow + (p + 2) * D_IN);

    // fragment reads (both layers up front -> max ILP)
    short8 b2[5], b1[4];
    #pragma unroll
    for (int kt = 0; kt < 5; ++kt)
      b2[kt] = *(const short8*)(RB + rbo + lgrp * 8 + kt * 32);
    #pragma unroll
    for (int kt = 0; kt < 4; ++kt)
      b1[kt] = *(const short8*)(RB + rbo + 64 + lgrp * 8 + kt * 32);

    // L2(p): gates^T = [Whh2|Wih2] * [h2|h1]^T
    f32x4 acc2[2];
    #pragma unroll
    for (int mt = 0; mt < 2; ++mt) {
      acc2[mt] = f32x4{ bias2[mt][0], bias2[mt][1], bias2[mt][2], bias2[mt][3] };
      #pragma unroll
      for (int kt = 0; kt < 5; ++kt)
        acc2[mt] = __builtin_amdgcn_mfma_f32_16x16x32_bf16(a2[mt][kt], b2[kt], acc2[mt], 0, 0, 0);
    }
    // L1(p+1): gates^T = [Whh1|Wih1] * [h1|x]^T
    f32x4 acc1[3];
    #pragma unroll
    for (int mt = 0; mt < 3; ++mt) {
      acc1[mt] = f32x4{ bias1[mt][0], bias1[mt][1], bias1[mt][2], bias1[mt][3] };
      #pragma unroll
      for (int kt = 0; kt < 4; ++kt)
        acc1[mt] = __builtin_amdgcn_mfma_f32_16x16x32_bf16(a1[mt][kt], b1[kt], acc1[mt], 0, 0, 0);
    }

    // activations + state update + writes (to the OTHER buffer -> no pre-write barrier)
    #pragma unroll
    for (int mt = 0; mt < 2; ++mt) {
      const float ig = sigf(acc2[mt][0]), fg = sigf(acc2[mt][1]);
      const float gg = tanhf_(acc2[mt][2]), og = sigf(acc2[mt][3]);
      c2[mt] = fg * c2[mt] + ig * gg;
      WB[rbo + w * 8 + mt * 4 + lgrp] = f2b(og * tanhf_(c2[mt]));
    }
    #pragma unroll
    for (int mt = 0; mt < 3; ++mt) {
      const float ig = sigf(acc1[mt][0]), fg = sigf(acc1[mt][1]);
      const float gg = tanhf_(acc1[mt][2]), og = sigf(acc1[mt][3]);
      c1[mt] = fg * c1[mt] + ig * gg;
      WB[rbo + 64 + w * 12 + mt * 4 + lgrp] = f2b(og * tanhf_(c1[mt]));
    }
    if (w == 0 && p + 2 < T_LEN) {
      unsigned pk = (unsigned)f2b(xv.x) | ((unsigned)f2b(xv.y) << 16);
      *(unsigned*)&WB[lrow * KPAD + 160 + lgrp * 2] = pk;
    }
    __syncthreads();
  }

  // ---------- final phase: L2(T-1); final h2 kept fp32 for the FC head ----------
  {
    const unsigned short* RB = &Hc[(T_LEN - 1) & 1][0];
    short8 b2[5];
    #pragma unroll
    for (int kt = 0; kt < 5; ++kt)
      b2[kt] = *(const short8*)(RB + rbo + lgrp * 8 + kt * 32);
    #pragma unroll
    for (int mt = 0; mt < 2; ++mt) {
      f32x4 acc = { bias2[mt][0], bias2[mt][1], bias2[mt][2], bias2[mt][3] };
      #pragma unroll
      for (int kt = 0; kt < 5; ++kt)
        acc = __builtin_amdgcn_mfma_f32_16x16x32_bf16(a2[mt][kt], b2[kt], acc, 0, 0, 0);
      const float ig = sigf(acc[0]), fg = sigf(acc[1]);
      const float gg = tanhf_(acc[2]), og = sigf(acc[3]);
      const float cf = fg * c2[mt] + ig * gg;
      h2f[lrow][w * 8 + mt * 4 + lgrp] = og * tanhf_(cf);
    }
  }
  __syncthreads();

  // ---- FC head: out = relu(h2 @ fc1w^T + fc1b) @ fcow^T + fcob ----
  for (int p = tid; p < BM * NH2; p += 512) {
    const int col = p >> 6;
    const int j   = p & 63;
    float s = fc1b[j];
    const float* wr = fc1w + j * NH2;
    #pragma unroll 8
    for (int k = 0; k < NH2; ++k) s += h2f[col][k] * wr[k];
    fcb[col][j] = fmaxf(s, 0.0f);
  }
  __syncthreads();
  if (tid < BM * HOR) {
    const int col = tid / HOR;
    const int oc  = tid - col * HOR;
    float s = fcob[oc];
    const float* wr = fcow + oc * NH2;
    #pragma unroll 8
    for (int k = 0; k < NH2; ++k) s += fcb[col][k] * wr[k];
    out[(size_t)(b0 + col) * HOR + oc] = s;
  }
}

} // namespace

extern "C" void kernel_launch(void* const* d_in, const int* in_sizes, int n_in,
                              void* d_out, int out_size, void* d_ws, size_t ws_size,
                              hipStream_t stream) {
  const float* x    = (const float*)d_in[0];
  const float* Wih1 = (const float*)d_in[1];
  const float* Whh1 = (const float*)d_in[2];
  const float* bih1 = (const float*)d_in[3];
  const float* bhh1 = (const float*)d_in[4];
  const float* Wih2 = (const float*)d_in[5];
  const float* Whh2 = (const float*)d_in[6];
  const float* bih2 = (const float*)d_in[7];
  const float* bhh2 = (const float*)d_in[8];
  const float* fc1w = (const float*)d_in[9];
  const float* fc1b = (const float*)d_in[10];
  const float* fcow = (const float*)d_in[11];
  const float* fcob = (const float*)d_in[12];
  float* out = (float*)d_out;

  const int Btot = in_sizes[0] / (T_LEN * D_IN);   // 4096
  const int nblk = Btot / BM;                       // 256 workgroups

  lstm_forecaster<<<dim3(nblk), dim3(512), 0, stream>>>(
      x, Wih1, Whh1, bih1, bhh1, Wih2, Whh2, bih2, bhh2,
      fc1w, fc1b, fcow, fcob, out);
}

// Round 3
// 343.475 us; speedup vs baseline: 2.0234x; 1.0529x over previous
//
#include <hip/hip_runtime.h>
#include <hip/hip_bf16.h>

namespace {

constexpr int T_LEN = 336;
constexpr int D_IN  = 8;
constexpr int NH1   = 96;   // layer1 hidden
constexpr int NH2   = 64;   // layer2 hidden
constexpr int HOR   = 24;   // output horizon
constexpr int BM    = 16;   // batch rows per workgroup
constexpr int KPAD  = 200;  // LDS row stride (bf16 elems): 400 B, 16B-aligned

// Per-row slot layout in each state buffer:
//   [0,64)=h2, [64,160)=h1, [160,168)=x_t, [168,192)=zero pad (never written)

typedef __attribute__((ext_vector_type(8))) short short8;
typedef __attribute__((ext_vector_type(4))) float f32x4;

__device__ inline unsigned short f2b(float f) {
  union { float f; unsigned u; } v; v.f = f;
  unsigned r = v.u + 0x7fffu + ((v.u >> 16) & 1u);   // RNE to bf16
  return (unsigned short)(r >> 16);
}

__device__ inline short8 pack8(float4 p0, float4 p1) {
  short8 f;
  f[0]=(short)f2b(p0.x); f[1]=(short)f2b(p0.y); f[2]=(short)f2b(p0.z); f[3]=(short)f2b(p0.w);
  f[4]=(short)f2b(p1.x); f[5]=(short)f2b(p1.y); f[6]=(short)f2b(p1.z); f[7]=(short)f2b(p1.w);
  return f;
}

// single-instruction packed f32->bf16 (RNE), lo<-a, hi<-b
__device__ inline unsigned cvt_pk_bf16(float a, float b) {
  unsigned r;
  asm("v_cvt_pk_bf16_f32 %0, %1, %2" : "=v"(r) : "v"(a), "v"(b));
  return r;
}

// fast activations: v_rcp_f32 (~1 ulp; bf16 state rounding dominates by 4 orders)
__device__ inline float sigf(float x)   { return __builtin_amdgcn_rcpf(1.0f + __expf(-x)); }
__device__ inline float tanhf_(float x) { return 1.0f - 2.0f * __builtin_amdgcn_rcpf(1.0f + __expf(2.0f * x)); }

__global__ __launch_bounds__(1024, 4) void lstm_forecaster(
    const float* __restrict__ x,
    const float* __restrict__ Wih1, const float* __restrict__ Whh1,
    const float* __restrict__ bih1, const float* __restrict__ bhh1,
    const float* __restrict__ Wih2, const float* __restrict__ Whh2,
    const float* __restrict__ bih2, const float* __restrict__ bhh2,
    const float* __restrict__ fc1w, const float* __restrict__ fc1b,
    const float* __restrict__ fcow, const float* __restrict__ fcob,
    float* __restrict__ out)
{
  __shared__ unsigned short Hc[2][BM * KPAD];   // double-buffered state
  __shared__ float h2f[BM][NH2];
  __shared__ float fcb[BM][NH2 + 4];

  const int tid  = threadIdx.x;
  const int w    = tid >> 6;   // wave id 0..15
  const int l    = tid & 63;   // lane
  const int lrow = l & 15;     // MFMA A-row / B-col / D-col (batch row)
  const int lgrp = l >> 4;     // 0..3
  const int b0   = blockIdx.x * BM;
  const bool isL1 = (w < 8);   // waves 0-7: layer1 (12 cells each); 8-15: layer2 (8 cells each)
  const int  wv   = isL1 ? w : (w - 8);

  // x streaming: wave 8 (an L2 wave - lighter duty) covers (row=lrow, float-pair j=lgrp)
  const float* xrow = x + (size_t)(b0 + lrow) * (T_LEN * D_IN) + lgrp * 2;
  float2 xv = make_float2(0.0f, 0.0f);
  if (w == 8) xv = *(const float2*)(xrow);          // x(0), issued early

  // zero both state buffers (h=0, pad stays 0 forever)
  for (int i = tid; i < 2 * BM * KPAD; i += 1024) ((unsigned short*)Hc)[i] = 0;

  // ---------- weight A-fragments (branch-shared register arrays) ----------
  // lane's 4 acc regs = i,f,g,o of one cell (row-permuted weights)
  short8 af[12];   // L1: [mt*4+kt] (3x4), K=[h1|x|pad]=128 ; L2: [mt*5+kt] (2x5), K=[h2|h1]=160
  float  bs[12];   // [mt*4+r]
  if (isL1) {
    #pragma unroll
    for (int mt = 0; mt < 3; ++mt) {
      const int gate = lrow & 3;
      const int cell = wv * 12 + mt * 4 + (lrow >> 2);
      const int wrow = NH1 * gate + cell;             // row in [0,384)
      #pragma unroll
      for (int kt = 0; kt < 4; ++kt) {
        const int kb = kt * 32 + lgrp * 8;
        if (kb < NH1) {
          af[mt*4+kt] = pack8(*(const float4*)(Whh1 + wrow * NH1 + kb),
                              *(const float4*)(Whh1 + wrow * NH1 + kb + 4));
        } else if (kb == NH1) {
          af[mt*4+kt] = pack8(*(const float4*)(Wih1 + wrow * D_IN),
                              *(const float4*)(Wih1 + wrow * D_IN + 4));
        } else {
          short8 z;
          #pragma unroll
          for (int e = 0; e < 8; ++e) z[e] = 0;
          af[mt*4+kt] = z;
        }
      }
      const int bcell = wv * 12 + mt * 4 + lgrp;      // C/D layout: row = 4*lgrp + r
      #pragma unroll
      for (int r = 0; r < 4; ++r)
        bs[mt*4+r] = bih1[NH1 * r + bcell] + bhh1[NH1 * r + bcell];
    }
  } else {
    #pragma unroll
    for (int mt = 0; mt < 2; ++mt) {
      const int gate = lrow & 3;
      const int cell = wv * 8 + mt * 4 + (lrow >> 2);
      const int wrow = NH2 * gate + cell;             // row in [0,256)
      #pragma unroll
      for (int kt = 0; kt < 5; ++kt) {
        const int kb = kt * 32 + lgrp * 8;
        if (kb < NH2) {
          af[mt*5+kt] = pack8(*(const float4*)(Whh2 + wrow * NH2 + kb),
                              *(const float4*)(Whh2 + wrow * NH2 + kb + 4));
        } else {
          af[mt*5+kt] = pack8(*(const float4*)(Wih2 + wrow * NH1 + (kb - NH2)),
                              *(const float4*)(Wih2 + wrow * NH1 + (kb - NH2) + 4));
        }
      }
      const int bcell = wv * 8 + mt * 4 + lgrp;
      #pragma unroll
      for (int r = 0; r < 4; ++r)
        bs[mt*4+r] = bih2[NH2 * r + bcell] + bhh2[NH2 * r + bcell];
    }
  }

  __syncthreads();                                  // zeros visible
  if (w == 8) {                                     // stage x(0) into buf1 (read buf of peel)
    *(unsigned*)&Hc[1][lrow * KPAD + 160 + lgrp * 2] = cvt_pk_bf16(xv.x, xv.y);
  }
  __syncthreads();                                  // x(0) visible

  float c[3] = {0.0f, 0.0f, 0.0f};
  const int rbo = lrow * KPAD;                      // per-row base offset

  // ---------- peel: L1(0) (reads buf1 -> writes buf0); wave8 stages x(1) into buf0 ----------
  {
    if (w == 8) {
      xv = *(const float2*)(xrow + D_IN);
      *(unsigned*)&Hc[0][rbo + 160 + lgrp * 2] = cvt_pk_bf16(xv.x, xv.y);
    }
    if (isL1) {
      short8 bf[4];
      #pragma unroll
      for (int kt = 0; kt < 4; ++kt)
        bf[kt] = *(const short8*)(&Hc[1][rbo + 64 + lgrp * 8 + kt * 32]);
      #pragma unroll
      for (int mt = 0; mt < 3; ++mt) {
        f32x4 acc = { bs[mt*4+0], bs[mt*4+1], bs[mt*4+2], bs[mt*4+3] };
        #pragma unroll
        for (int kt = 0; kt < 4; ++kt)
          acc = __builtin_amdgcn_mfma_f32_16x16x32_bf16(af[mt*4+kt], bf[kt], acc, 0, 0, 0);
        const float ig = sigf(acc[0]), fg = sigf(acc[1]);
        const float gg = tanhf_(acc[2]), og = sigf(acc[3]);
        c[mt] = fg * c[mt] + ig * gg;
        Hc[0][rbo + 64 + wv * 12 + mt * 4 + lgrp] = f2b(og * tanhf_(c[mt]));
      }
    }
    __syncthreads();
  }

  // ---------- main loop: phase p = L2(p) (waves 8-15) || L1(p+1) (waves 0-7); ONE barrier ----------
  for (int p = 0; p < T_LEN - 1; ++p) {
    const unsigned short* RB = &Hc[p & 1][0];
    unsigned short*       WB = &Hc[(p & 1) ^ 1][0];

    if (isL1) {
      short8 bf[4];
      #pragma unroll
      for (int kt = 0; kt < 4; ++kt)
        bf[kt] = *(const short8*)(RB + rbo + 64 + lgrp * 8 + kt * 32);
      float h1v[3];
      #pragma unroll
      for (int mt = 0; mt < 3; ++mt) {
        f32x4 acc = { bs[mt*4+0], bs[mt*4+1], bs[mt*4+2], bs[mt*4+3] };
        #pragma unroll
        for (int kt = 0; kt < 4; ++kt)
          acc = __builtin_amdgcn_mfma_f32_16x16x32_bf16(af[mt*4+kt], bf[kt], acc, 0, 0, 0);
        const float ig = sigf(acc[0]), fg = sigf(acc[1]);
        const float gg = tanhf_(acc[2]), og = sigf(acc[3]);
        c[mt] = fg * c[mt] + ig * gg;
        h1v[mt] = og * tanhf_(c[mt]);
      }
      const unsigned pk01 = cvt_pk_bf16(h1v[0], h1v[1]);
      const unsigned pk2  = cvt_pk_bf16(h1v[2], h1v[2]);
      WB[rbo + 64 + wv * 12 + 0 + lgrp] = (unsigned short)pk01;
      WB[rbo + 64 + wv * 12 + 4 + lgrp] = (unsigned short)(pk01 >> 16);
      WB[rbo + 64 + wv * 12 + 8 + lgrp] = (unsigned short)pk2;
    } else {
      if (w == 8 && p + 2 < T_LEN)                  // x(p+2), hidden under this phase
        xv = *(const float2*)(xrow + (p + 2) * D_IN);
      short8 bf[5];
      #pragma unroll
      for (int kt = 0; kt < 5; ++kt)
        bf[kt] = *(const short8*)(RB + rbo + lgrp * 8 + kt * 32);
      float h2v[2];
      #pragma unroll
      for (int mt = 0; mt < 2; ++mt) {
        f32x4 acc = { bs[mt*4+0], bs[mt*4+1], bs[mt*4+2], bs[mt*4+3] };
        #pragma unroll
        for (int kt = 0; kt < 5; ++kt)
          acc = __builtin_amdgcn_mfma_f32_16x16x32_bf16(af[mt*5+kt], bf[kt], acc, 0, 0, 0);
        const float ig = sigf(acc[0]), fg = sigf(acc[1]);
        const float gg = tanhf_(acc[2]), og = sigf(acc[3]);
        c[mt] = fg * c[mt] + ig * gg;
        h2v[mt] = og * tanhf_(c[mt]);
      }
      const unsigned pk = cvt_pk_bf16(h2v[0], h2v[1]);
      WB[rbo + wv * 8 + 0 + lgrp] = (unsigned short)pk;
      WB[rbo + wv * 8 + 4 + lgrp] = (unsigned short)(pk >> 16);
      if (w == 8 && p + 2 < T_LEN)
        *(unsigned*)&WB[rbo + 160 + lgrp * 2] = cvt_pk_bf16(xv.x, xv.y);
    }
    __syncthreads();
  }

  // ---------- final phase: L2(T-1); final h2 kept fp32 for the FC head ----------
  if (!isL1) {
    const unsigned short* RB = &Hc[(T_LEN - 1) & 1][0];
    short8 bf[5];
    #pragma unroll
    for (int kt = 0; kt < 5; ++kt)
      bf[kt] = *(const short8*)(RB + rbo + lgrp * 8 + kt * 32);
    #pragma unroll
    for (int mt = 0; mt < 2; ++mt) {
      f32x4 acc = { bs[mt*4+0], bs[mt*4+1], bs[mt*4+2], bs[mt*4+3] };
      #pragma unroll
      for (int kt = 0; kt < 5; ++kt)
        acc = __builtin_amdgcn_mfma_f32_16x16x32_bf16(af[mt*5+kt], bf[kt], acc, 0, 0, 0);
      const float ig = sigf(acc[0]), fg = sigf(acc[1]);
      const float gg = tanhf_(acc[2]), og = sigf(acc[3]);
      const float cf = fg * c[mt] + ig * gg;
      h2f[lrow][wv * 8 + mt * 4 + lgrp] = og * tanhf_(cf);
    }
  }
  __syncthreads();

  // ---- FC head: out = relu(h2 @ fc1w^T + fc1b) @ fcow^T + fcob ----
  {
    const int col = tid >> 6;                       // 1024 threads == BM*NH2 exactly
    const int j   = tid & 63;
    float s = fc1b[j];
    const float* wr = fc1w + j * NH2;
    #pragma unroll 8
    for (int k = 0; k < NH2; ++k) s += h2f[col][k] * wr[k];
    fcb[col][j] = fmaxf(s, 0.0f);
  }
  __syncthreads();
  if (tid < BM * HOR) {
    const int col = tid / HOR;
    const int oc  = tid - col * HOR;
    float s = fcob[oc];
    const float* wr = fcow + oc * NH2;
    #pragma unroll 8
    for (int k = 0; k < NH2; ++k) s += fcb[col][k] * wr[k];
    out[(size_t)(b0 + col) * HOR + oc] = s;
  }
}

} // namespace

extern "C" void kernel_launch(void* const* d_in, const int* in_sizes, int n_in,
                              void* d_out, int out_size, void* d_ws, size_t ws_size,
                              hipStream_t stream) {
  const float* x    = (const float*)d_in[0];
  const float* Wih1 = (const float*)d_in[1];
  const float* Whh1 = (const float*)d_in[2];
  const float* bih1 = (const float*)d_in[3];
  const float* bhh1 = (const float*)d_in[4];
  const float* Wih2 = (const float*)d_in[5];
  const float* Whh2 = (const float*)d_in[6];
  const float* bih2 = (const float*)d_in[7];
  const float* bhh2 = (const float*)d_in[8];
  const float* fc1w = (const float*)d_in[9];
  const float* fc1b = (const float*)d_in[10];
  const float* fcow = (const float*)d_in[11];
  const float* fcob = (const float*)d_in[12];
  float* out = (float*)d_out;

  const int Btot = in_sizes[0] / (T_LEN * D_IN);   // 4096
  const int nblk = Btot / BM;                       // 256 workgroups

  lstm_forecaster<<<dim3(nblk), dim3(1024), 0, stream>>>(
      x, Wih1, Whh1, bih1, bhh1, Wih2, Whh2, bih2, bhh2,
      fc1w, fc1b, fcow, fcob, out);
}

// Round 4
// 303.598 us; speedup vs baseline: 2.2891x; 1.1313x over previous
//
#include <hip/hip_runtime.h>
#include <hip/hip_bf16.h>

namespace {

constexpr int T_LEN = 336;
constexpr int D_IN  = 8;
constexpr int NH1   = 96;   // layer1 hidden
constexpr int NH2   = 64;   // layer2 hidden
constexpr int HOR   = 24;   // output horizon
constexpr int BM    = 16;   // batch rows per workgroup
constexpr int KPAD  = 200;  // LDS row stride (bf16 elems): 400 B, 16B-aligned

// Per-row slot layout in each state buffer:
//   [0,64)=h2, [64,160)=h1, [160,168)=x_t, [168,192)=zero pad (never written)

typedef __attribute__((ext_vector_type(8))) short short8;
typedef __attribute__((ext_vector_type(4))) float f32x4;

constexpr float LOG2E = 1.4426950408889634f;

__device__ inline unsigned short f2b(float f) {
  union { float f; unsigned u; } v; v.f = f;
  unsigned r = v.u + 0x7fffu + ((v.u >> 16) & 1u);   // RNE to bf16
  return (unsigned short)(r >> 16);
}

// pack 8 floats -> bf16x8, scaling each by s (gate-dependent exp2-domain prescale)
__device__ inline short8 pack8s(float4 p0, float4 p1, float s) {
  short8 f;
  f[0]=(short)f2b(p0.x*s); f[1]=(short)f2b(p0.y*s); f[2]=(short)f2b(p0.z*s); f[3]=(short)f2b(p0.w*s);
  f[4]=(short)f2b(p1.x*s); f[5]=(short)f2b(p1.y*s); f[6]=(short)f2b(p1.z*s); f[7]=(short)f2b(p1.w*s);
  return f;
}

// single-instruction packed f32->bf16 (RNE), lo<-a, hi<-b
__device__ inline unsigned cvt_pk_bf16(float a, float b) {
  unsigned r;
  asm("v_cvt_pk_bf16_f32 %0, %1, %2" : "=v"(r) : "v"(a), "v"(b));
  return r;
}

#if __has_builtin(__builtin_amdgcn_exp2f)
__device__ inline float exp2_(float x) { return __builtin_amdgcn_exp2f(x); }
#else
__device__ inline float exp2_(float x) { float r; asm("v_exp_f32 %0, %1" : "=v"(r) : "v"(x)); return r; }
#endif

// One LSTM cell update from exp2-domain gate pre-activations.
// acc = { yi, yf, yg, yo } where yi = -log2e*a_i (etc.), yg = -2log2e*a_g.
// 5 exp + 2 rcp (trans) instead of 10; accuracy loss < 1e-6.
__device__ inline float cell_update(const f32x4 acc, float& c) {
  const float Ei = exp2_(acc[0]);
  const float Ef = exp2_(acc[1]);
  const float Eg = exp2_(acc[2]);
  const float Eo = exp2_(acc[3]);
  const float Di = 1.0f + Ei, Df = 1.0f + Ef, Dg = 1.0f + Eg, Dq = 1.0f + Eo;
  const float Pig = Di * Dg;
  const float R   = __builtin_amdgcn_rcpf(Pig * Df);   // 1/(Di*Dg*Df)
  const float fv  = Pig * R;                           // sigmoid(f)
  const float ig  = (1.0f - Eg) * (Df * R);            // sigmoid(i)*tanh(g)
  c = fmaf(fv, c, ig);
  const float yc = fminf(c * (-2.0f * LOG2E), 60.0f);  // clamp: overflow-safe, err<2^-60
  const float Ec = exp2_(yc);
  const float R2 = __builtin_amdgcn_rcpf(Dq * (1.0f + Ec));
  return (1.0f - Ec) * R2;                             // sigmoid(o)*tanh(c)
}

__global__ __launch_bounds__(1024, 4) void lstm_forecaster(
    const float* __restrict__ x,
    const float* __restrict__ Wih1, const float* __restrict__ Whh1,
    const float* __restrict__ bih1, const float* __restrict__ bhh1,
    const float* __restrict__ Wih2, const float* __restrict__ Whh2,
    const float* __restrict__ bih2, const float* __restrict__ bhh2,
    const float* __restrict__ fc1w, const float* __restrict__ fc1b,
    const float* __restrict__ fcow, const float* __restrict__ fcob,
    float* __restrict__ out)
{
  __shared__ unsigned short Hc[2][BM * KPAD];   // double-buffered state
  __shared__ float h2f[BM][NH2];
  __shared__ float fcb[BM][NH2 + 4];

  const int tid  = threadIdx.x;
  const int w    = tid >> 6;   // wave id 0..15
  const int l    = tid & 63;   // lane
  const int lrow = l & 15;     // MFMA A-row / B-col / D-col (batch row)
  const int lgrp = l >> 4;     // 0..3
  const int b0   = blockIdx.x * BM;
  const bool isL1 = (w < 8);   // waves 0-7: layer1 (12 cells each); 8-15: layer2 (8 cells each)
  const int  wv   = isL1 ? w : (w - 8);

  // x streaming: wave 8 (an L2 wave - lighter duty) covers (row=lrow, float-pair j=lgrp)
  const float* xrow = x + (size_t)(b0 + lrow) * (T_LEN * D_IN) + lgrp * 2;
  float2 xv = make_float2(0.0f, 0.0f);
  if (w == 8) xv = *(const float2*)(xrow);          // x(0), issued early

  // zero both state buffers (h=0, pad stays 0 forever)
  for (int i = tid; i < 2 * BM * KPAD; i += 1024) ((unsigned short*)Hc)[i] = 0;

  // ---------- weight A-fragments (branch-shared register arrays) ----------
  // lane's 4 acc regs = i,f,g,o of one cell (row-permuted weights).
  // Rows pre-scaled into exp2 domain: i,f,o by -log2e; g by -2log2e.
  short8 af[12];   // L1: [mt*4+kt] (3x4), K=[h1|x|pad]=128 ; L2: [mt*5+kt] (2x5), K=[h2|h1]=160
  float  bs[12];   // [mt*4+r]
  if (isL1) {
    #pragma unroll
    for (int mt = 0; mt < 3; ++mt) {
      const int gate = lrow & 3;
      const float gs = (gate == 2) ? (-2.0f * LOG2E) : (-LOG2E);
      const int cell = wv * 12 + mt * 4 + (lrow >> 2);
      const int wrow = NH1 * gate + cell;             // row in [0,384)
      #pragma unroll
      for (int kt = 0; kt < 4; ++kt) {
        const int kb = kt * 32 + lgrp * 8;
        if (kb < NH1) {
          af[mt*4+kt] = pack8s(*(const float4*)(Whh1 + wrow * NH1 + kb),
                               *(const float4*)(Whh1 + wrow * NH1 + kb + 4), gs);
        } else if (kb == NH1) {
          af[mt*4+kt] = pack8s(*(const float4*)(Wih1 + wrow * D_IN),
                               *(const float4*)(Wih1 + wrow * D_IN + 4), gs);
        } else {
          short8 z;
          #pragma unroll
          for (int e = 0; e < 8; ++e) z[e] = 0;
          af[mt*4+kt] = z;
        }
      }
      const int bcell = wv * 12 + mt * 4 + lgrp;      // C/D layout: row = 4*lgrp + r
      #pragma unroll
      for (int r = 0; r < 4; ++r) {
        const float bsc = (r == 2) ? (-2.0f * LOG2E) : (-LOG2E);
        bs[mt*4+r] = bsc * (bih1[NH1 * r + bcell] + bhh1[NH1 * r + bcell]);
      }
    }
  } else {
    #pragma unroll
    for (int mt = 0; mt < 2; ++mt) {
      const int gate = lrow & 3;
      const float gs = (gate == 2) ? (-2.0f * LOG2E) : (-LOG2E);
      const int cell = wv * 8 + mt * 4 + (lrow >> 2);
      const int wrow = NH2 * gate + cell;             // row in [0,256)
      #pragma unroll
      for (int kt = 0; kt < 5; ++kt) {
        const int kb = kt * 32 + lgrp * 8;
        if (kb < NH2) {
          af[mt*5+kt] = pack8s(*(const float4*)(Whh2 + wrow * NH2 + kb),
                               *(const float4*)(Whh2 + wrow * NH2 + kb + 4), gs);
        } else {
          af[mt*5+kt] = pack8s(*(const float4*)(Wih2 + wrow * NH1 + (kb - NH2)),
                               *(const float4*)(Wih2 + wrow * NH1 + (kb - NH2) + 4), gs);
        }
      }
      const int bcell = wv * 8 + mt * 4 + lgrp;
      #pragma unroll
      for (int r = 0; r < 4; ++r) {
        const float bsc = (r == 2) ? (-2.0f * LOG2E) : (-LOG2E);
        bs[mt*4+r] = bsc * (bih2[NH2 * r + bcell] + bhh2[NH2 * r + bcell]);
      }
    }
  }

  __syncthreads();                                  // zeros visible
  if (w == 8) {                                     // stage x(0) into buf1 (read buf of peel)
    *(unsigned*)&Hc[1][lrow * KPAD + 160 + lgrp * 2] = cvt_pk_bf16(xv.x, xv.y);
  }
  __syncthreads();                                  // x(0) visible

  float c[3] = {0.0f, 0.0f, 0.0f};
  const int rbo = lrow * KPAD;                      // per-row base offset

  // ---------- peel: L1(0) (reads buf1 -> writes buf0); wave8 stages x(1) into buf0 ----------
  {
    if (w == 8) {
      xv = *(const float2*)(xrow + D_IN);
      *(unsigned*)&Hc[0][rbo + 160 + lgrp * 2] = cvt_pk_bf16(xv.x, xv.y);
    }
    if (isL1) {
      short8 bf[4];
      #pragma unroll
      for (int kt = 0; kt < 4; ++kt)
        bf[kt] = *(const short8*)(&Hc[1][rbo + 64 + lgrp * 8 + kt * 32]);
      #pragma unroll
      for (int mt = 0; mt < 3; ++mt) {
        f32x4 acc = { bs[mt*4+0], bs[mt*4+1], bs[mt*4+2], bs[mt*4+3] };
        #pragma unroll
        for (int kt = 0; kt < 4; ++kt)
          acc = __builtin_amdgcn_mfma_f32_16x16x32_bf16(af[mt*4+kt], bf[kt], acc, 0, 0, 0);
        Hc[0][rbo + 64 + wv * 12 + mt * 4 + lgrp] = f2b(cell_update(acc, c[mt]));
      }
    }
    __syncthreads();
  }

  // ---------- main loop: phase p = L2(p) (waves 8-15) || L1(p+1) (waves 0-7); ONE barrier ----------
  #pragma unroll 2
  for (int p = 0; p < T_LEN - 1; ++p) {
    const unsigned short* RB = &Hc[p & 1][0];
    unsigned short*       WB = &Hc[(p & 1) ^ 1][0];

    if (isL1) {
      short8 bf[4];
      #pragma unroll
      for (int kt = 0; kt < 4; ++kt)
        bf[kt] = *(const short8*)(RB + rbo + 64 + lgrp * 8 + kt * 32);
      float h1v[3];
      #pragma unroll
      for (int mt = 0; mt < 3; ++mt) {
        f32x4 acc = { bs[mt*4+0], bs[mt*4+1], bs[mt*4+2], bs[mt*4+3] };
        #pragma unroll
        for (int kt = 0; kt < 4; ++kt)
          acc = __builtin_amdgcn_mfma_f32_16x16x32_bf16(af[mt*4+kt], bf[kt], acc, 0, 0, 0);
        h1v[mt] = cell_update(acc, c[mt]);
      }
      const unsigned pk01 = cvt_pk_bf16(h1v[0], h1v[1]);
      const unsigned pk2  = cvt_pk_bf16(h1v[2], h1v[2]);
      WB[rbo + 64 + wv * 12 + 0 + lgrp] = (unsigned short)pk01;
      WB[rbo + 64 + wv * 12 + 4 + lgrp] = (unsigned short)(pk01 >> 16);
      WB[rbo + 64 + wv * 12 + 8 + lgrp] = (unsigned short)pk2;
    } else {
      if (w == 8 && p + 2 < T_LEN)                  // x(p+2), hidden under this phase
        xv = *(const float2*)(xrow + (p + 2) * D_IN);
      short8 bf[5];
      #pragma unroll
      for (int kt = 0; kt < 5; ++kt)
        bf[kt] = *(const short8*)(RB + rbo + lgrp * 8 + kt * 32);
      float h2v[2];
      #pragma unroll
      for (int mt = 0; mt < 2; ++mt) {
        f32x4 acc = { bs[mt*4+0], bs[mt*4+1], bs[mt*4+2], bs[mt*4+3] };
        #pragma unroll
        for (int kt = 0; kt < 5; ++kt)
          acc = __builtin_amdgcn_mfma_f32_16x16x32_bf16(af[mt*5+kt], bf[kt], acc, 0, 0, 0);
        h2v[mt] = cell_update(acc, c[mt]);
      }
      const unsigned pk = cvt_pk_bf16(h2v[0], h2v[1]);
      WB[rbo + wv * 8 + 0 + lgrp] = (unsigned short)pk;
      WB[rbo + wv * 8 + 4 + lgrp] = (unsigned short)(pk >> 16);
      if (w == 8 && p + 2 < T_LEN)
        *(unsigned*)&WB[rbo + 160 + lgrp * 2] = cvt_pk_bf16(xv.x, xv.y);
    }
    __syncthreads();
  }

  // ---------- final phase: L2(T-1); final h2 kept fp32 for the FC head ----------
  if (!isL1) {
    const unsigned short* RB = &Hc[(T_LEN - 1) & 1][0];
    short8 bf[5];
    #pragma unroll
    for (int kt = 0; kt < 5; ++kt)
      bf[kt] = *(const short8*)(RB + rbo + lgrp * 8 + kt * 32);
    #pragma unroll
    for (int mt = 0; mt < 2; ++mt) {
      f32x4 acc = { bs[mt*4+0], bs[mt*4+1], bs[mt*4+2], bs[mt*4+3] };
      #pragma unroll
      for (int kt = 0; kt < 5; ++kt)
        acc = __builtin_amdgcn_mfma_f32_16x16x32_bf16(af[mt*5+kt], bf[kt], acc, 0, 0, 0);
      h2f[lrow][wv * 8 + mt * 4 + lgrp] = cell_update(acc, c[mt]);
    }
  }
  __syncthreads();

  // ---- FC head: out = relu(h2 @ fc1w^T + fc1b) @ fcow^T + fcob ----
  {
    const int col = tid >> 6;                       // 1024 threads == BM*NH2 exactly
    const int j   = tid & 63;
    float s = fc1b[j];
    const float* wr = fc1w + j * NH2;
    #pragma unroll 8
    for (int k = 0; k < NH2; ++k) s += h2f[col][k] * wr[k];
    fcb[col][j] = fmaxf(s, 0.0f);
  }
  __syncthreads();
  if (tid < BM * HOR) {
    const int col = tid / HOR;
    const int oc  = tid - col * HOR;
    float s = fcob[oc];
    const float* wr = fcow + oc * NH2;
    #pragma unroll 8
    for (int k = 0; k < NH2; ++k) s += fcb[col][k] * wr[k];
    out[(size_t)(b0 + col) * HOR + oc] = s;
  }
}

} // namespace

extern "C" void kernel_launch(void* const* d_in, const int* in_sizes, int n_in,
                              void* d_out, int out_size, void* d_ws, size_t ws_size,
                              hipStream_t stream) {
  const float* x    = (const float*)d_in[0];
  const float* Wih1 = (const float*)d_in[1];
  const float* Whh1 = (const float*)d_in[2];
  const float* bih1 = (const float*)d_in[3];
  const float* bhh1 = (const float*)d_in[4];
  const float* Wih2 = (const float*)d_in[5];
  const float* Whh2 = (const float*)d_in[6];
  const float* bih2 = (const float*)d_in[7];
  const float* bhh2 = (const float*)d_in[8];
  const float* fc1w = (const float*)d_in[9];
  const float* fc1b = (const float*)d_in[10];
  const float* fcow = (const float*)d_in[11];
  const float* fcob = (const float*)d_in[12];
  float* out = (float*)d_out;

  const int Btot = in_sizes[0] / (T_LEN * D_IN);   // 4096
  const int nblk = Btot / BM;                       // 256 workgroups

  lstm_forecaster<<<dim3(nblk), dim3(1024), 0, stream>>>(
      x, Wih1, Whh1, bih1, bhh1, Wih2, Whh2, bih2, bhh2,
      fc1w, fc1b, fcow, fcob, out);
}